// Round 4
// baseline (248.818 us; speedup 1.0000x reference)
//
#include <hip/hip_runtime.h>
#include <stdint.h>

#define SEQ   512
#define NB    1024
#define NIN   64
#define NH    16
#define NCLS  6
#define GSTRIDE 20   // floats per gate row in LDS (16 data + 4 pad)
#define NGRP  (SEQ / 16)

typedef __attribute__((ext_vector_type(8))) short short8;
typedef __attribute__((ext_vector_type(4))) float f32x4;

// constants: gate pre-acts are pre-scaled so exp2 consumes them directly.
// i,f,o: z' = -log2e * z      -> sigma(z)  = rcp(1+exp2(z'))
// g:     z' = -2*log2e * z    -> sigma(2z) = rcp(1+exp2(z')); tanh(z)=2r-1
// c kept pre-scaled by K = -2*log2e (so exp2(C) = e^{-2c}); g-lane output
// constants fold K: act_g = K*tanh(g) = 2K*r - K.
#define LOG2E   1.4426950408889634f
#define NK_IFO  (-1.4426950408889634f)
#define NK_G    (-2.8853900817779268f)
#define KC      (-2.8853900817779268f)

// G chunk swizzle: physical chunk = logical chunk ^ ((row>>3)&3).
// Rationale: row base banks (20*row mod 32) repeat with period 8, so rows
// {r, r+8, r+16, ...} share a bank base; XOR-rotating their chunk index
// spreads the 8 aliasing lanes across all 4 chunks -> 2-way max (free).
#define GKEY(row) (((row) >> 3) & 3)

__device__ __forceinline__ float readlane_f(float v, int l) {
    return __int_as_float(__builtin_amdgcn_readlane(__float_as_int(v), l));
}

// Split fp32 -> bf16 hi + bf16 lo (truncation split; residual ~2^-16 relative)
__device__ __forceinline__ void split8(float4 u0, float4 u1, short8& hi, short8& lo) {
    float f[8] = {u0.x, u0.y, u0.z, u0.w, u1.x, u1.y, u1.z, u1.w};
    #pragma unroll
    for (int j = 0; j < 8; ++j) {
        uint32_t b = __float_as_uint(f[j]);
        uint16_t hb = (uint16_t)(b >> 16);
        hi[j] = (short)hb;
        float hf = __uint_as_float(((uint32_t)hb) << 16);
        lo[j] = (short)(uint16_t)(__float_as_uint(f[j] - hf) >> 16);
    }
}

// quad_perm broadcast via update_dpp (R4/R5-verified on gfx950)
__device__ __forceinline__ float quad_bcast0(float v) {
    return __int_as_float(__builtin_amdgcn_update_dpp(0, __float_as_int(v), 0x00, 0xF, 0xF, true));
}
__device__ __forceinline__ float quad_bcast1(float v) {
    return __int_as_float(__builtin_amdgcn_update_dpp(0, __float_as_int(v), 0x55, 0xF, 0xF, true));
}
__device__ __forceinline__ float quad_bcast2(float v) {
    return __int_as_float(__builtin_amdgcn_update_dpp(0, __float_as_int(v), 0xAA, 0xF, 0xF, true));
}
__device__ __forceinline__ float quad_bcast3(float v) {
    return __int_as_float(__builtin_amdgcn_update_dpp(0, __float_as_int(v), 0xFF, 0xF, 0xF, true));
}

__global__ __launch_bounds__(512, 2)
void lstm_ws_kernel(const float* __restrict__ x,
                    const float* __restrict__ w_ih,
                    const float* __restrict__ w_hh,
                    const float* __restrict__ b_ih,
                    const float* __restrict__ b_hh,
                    const float* __restrict__ w_fc,
                    const float* __restrict__ b_fc,
                    float* __restrict__ out)
{
    __shared__ float G [4][2][64 * GSTRIDE];   // 40 KB, pre-scaled gates (chunk-swizzled)
    __shared__ float HT[4][2][16 * NH];        //  8 KB, h history

    const int tid  = threadIdx.x;
    const int wid  = tid >> 6;       // 0..7
    const int lane = tid & 63;
    // Role permutation for SIMD pairing (HW maps wave -> SIMD wid%4):
    //   producers: wid 0,1,4,5 -> SIMDs 0,1,0,1  (two producers share a SIMD)
    //   consumers: wid 2,3,6,7 -> SIMDs 2,3,2,3  (two consumers share a SIMD)
    // Two independent recurrence chains interleave on SIMD2/3: one chain's
    // dependency stalls are filled by the other's ready ops.
    const bool producer = !(wid & 2);
    const int  e        = (wid & 1) | ((wid & 4) >> 1);   // chain 0..3 within block
    const int  b        = blockIdx.x * 4 + e;

    if (producer) {
        // ================= PRODUCER: x-GEMM + staging + FC =================
        const int ml   = lane & 15;      // MFMA A row (timestep) / B col
        const int half = lane >> 4;      // 0..3
        const int kk   = half * 8;

        short8 Bh[4][2], Bl[4][2];
        #pragma unroll
        for (int tau = 0; tau < 4; ++tau) {
            #pragma unroll
            for (int ch = 0; ch < 2; ++ch) {
                const float* wr = w_ih + (tau * 16 + ml) * NIN + ch * 32 + kk;
                float4 u0 = *(const float4*)wr;
                float4 u1 = *(const float4*)(wr + 4);
                split8(u0, u1, Bh[tau][ch], Bl[tau][ch]);
            }
        }
        // per-tile exp2 prescale + prescaled bias (gate row = tau*16 + ml; tau==2 is g)
        float nkt[4], bwk[4];
        int   gidx[4];   // swizzled chunk slot for this lane's 4 G rows
        #pragma unroll
        for (int tau = 0; tau < 4; ++tau) {
            nkt[tau] = (tau == 2) ? NK_G : NK_IFO;
            bwk[tau] = (b_ih[tau * 16 + ml] + b_hh[tau * 16 + ml]) * nkt[tau];
            const int row = ml * 4 + tau;
            gidx[tau] = row * GSTRIDE + (half ^ GKEY(row)) * 4;
        }

        const float* xbase = x + ((size_t)b * SEQ + ml) * NIN + kk;
        float4 px0 = *(const float4*)(xbase + 0);
        float4 px1 = *(const float4*)(xbase + 4);
        float4 px2 = *(const float4*)(xbase + 32);
        float4 px3 = *(const float4*)(xbase + 36);

        // prologue: compute G[0]
        {
            short8 a0h, a0l, a1h, a1l;
            split8(px0, px1, a0h, a0l);
            split8(px2, px3, a1h, a1l);
            #pragma unroll
            for (int tau = 0; tau < 4; ++tau) {
                f32x4 c_ = {0.f, 0.f, 0.f, 0.f};
                c_ = __builtin_amdgcn_mfma_f32_16x16x32_bf16(a0h, Bh[tau][0], c_, 0, 0, 0);
                c_ = __builtin_amdgcn_mfma_f32_16x16x32_bf16(a1h, Bh[tau][1], c_, 0, 0, 0);
                c_ = __builtin_amdgcn_mfma_f32_16x16x32_bf16(a0l, Bh[tau][0], c_, 0, 0, 0);
                c_ = __builtin_amdgcn_mfma_f32_16x16x32_bf16(a0h, Bl[tau][0], c_, 0, 0, 0);
                c_ = __builtin_amdgcn_mfma_f32_16x16x32_bf16(a1l, Bh[tau][1], c_, 0, 0, 0);
                c_ = __builtin_amdgcn_mfma_f32_16x16x32_bf16(a1h, Bl[tau][1], c_, 0, 0, 0);
                f32x4 s_;
                s_[0] = fmaf(c_[0], nkt[tau], bwk[tau]);
                s_[1] = fmaf(c_[1], nkt[tau], bwk[tau]);
                s_[2] = fmaf(c_[2], nkt[tau], bwk[tau]);
                s_[3] = fmaf(c_[3], nkt[tau], bwk[tau]);
                *(f32x4*)&G[e][0][gidx[tau]] = s_;
            }
        }
        {
            const float* xp = xbase + (size_t)16 * NIN;
            px0 = *(const float4*)(xp + 0);
            px1 = *(const float4*)(xp + 4);
            px2 = *(const float4*)(xp + 32);
            px3 = *(const float4*)(xp + 36);
        }
        __syncthreads();   // barrier 0: G[0] ready

        float accfc[NCLS];
        #pragma unroll
        for (int cls = 0; cls < NCLS; ++cls) accfc[cls] = 0.f;

        for (int g = 0; g < NGRP; ++g) {
            if (g < NGRP - 1) {
                short8 a0h, a0l, a1h, a1l;
                split8(px0, px1, a0h, a0l);
                split8(px2, px3, a1h, a1l);
                if (g < NGRP - 2) {
                    const float* xp = xbase + (size_t)(g + 2) * 16 * NIN;
                    px0 = *(const float4*)(xp + 0);
                    px1 = *(const float4*)(xp + 4);
                    px2 = *(const float4*)(xp + 32);
                    px3 = *(const float4*)(xp + 36);
                }
                #pragma unroll
                for (int tau = 0; tau < 4; ++tau) {
                    f32x4 c_ = {0.f, 0.f, 0.f, 0.f};
                    c_ = __builtin_amdgcn_mfma_f32_16x16x32_bf16(a0h, Bh[tau][0], c_, 0, 0, 0);
                    c_ = __builtin_amdgcn_mfma_f32_16x16x32_bf16(a1h, Bh[tau][1], c_, 0, 0, 0);
                    c_ = __builtin_amdgcn_mfma_f32_16x16x32_bf16(a0l, Bh[tau][0], c_, 0, 0, 0);
                    c_ = __builtin_amdgcn_mfma_f32_16x16x32_bf16(a0h, Bl[tau][0], c_, 0, 0, 0);
                    c_ = __builtin_amdgcn_mfma_f32_16x16x32_bf16(a1l, Bh[tau][1], c_, 0, 0, 0);
                    c_ = __builtin_amdgcn_mfma_f32_16x16x32_bf16(a1h, Bl[tau][1], c_, 0, 0, 0);
                    f32x4 s_;
                    s_[0] = fmaf(c_[0], nkt[tau], bwk[tau]);
                    s_[1] = fmaf(c_[1], nkt[tau], bwk[tau]);
                    s_[2] = fmaf(c_[2], nkt[tau], bwk[tau]);
                    s_[3] = fmaf(c_[3], nkt[tau], bwk[tau]);
                    *(f32x4*)&G[e][(g + 1) & 1][gidx[tau]] = s_;
                }
            }
            if (g > 0) {
                const int gp = g - 1;
                float4 h4 = *(float4*)&HT[e][gp & 1][lane * 4];
                #pragma unroll
                for (int cls = 0; cls < NCLS; ++cls) {
                    float4 wf = *(const float4*)(w_fc + cls * (SEQ * NH) + gp * 256 + lane * 4);
                    accfc[cls] = fmaf(h4.x, wf.x, accfc[cls]);
                    accfc[cls] = fmaf(h4.y, wf.y, accfc[cls]);
                    accfc[cls] = fmaf(h4.z, wf.z, accfc[cls]);
                    accfc[cls] = fmaf(h4.w, wf.w, accfc[cls]);
                }
            }
            __syncthreads();   // barrier g+1
        }
        {
            const int gp = NGRP - 1;
            float4 h4 = *(float4*)&HT[e][gp & 1][lane * 4];
            #pragma unroll
            for (int cls = 0; cls < NCLS; ++cls) {
                float4 wf = *(const float4*)(w_fc + cls * (SEQ * NH) + gp * 256 + lane * 4);
                accfc[cls] = fmaf(h4.x, wf.x, accfc[cls]);
                accfc[cls] = fmaf(h4.y, wf.y, accfc[cls]);
                accfc[cls] = fmaf(h4.z, wf.z, accfc[cls]);
                accfc[cls] = fmaf(h4.w, wf.w, accfc[cls]);
            }
        }
        #pragma unroll
        for (int cls = 0; cls < NCLS; ++cls) {
            float v = accfc[cls];
            v += __shfl_xor(v, 1);
            v += __shfl_xor(v, 2);
            v += __shfl_xor(v, 4);
            v += __shfl_xor(v, 8);
            v += __shfl_xor(v, 16);
            v += __shfl_xor(v, 32);
            accfc[cls] = v;
        }
        if (lane == 0) {
            #pragma unroll
            for (int cls = 0; cls < NCLS; ++cls)
                out[b * NCLS + cls] = accfc[cls] + b_fc[cls];
        }
    } else {
        // ================= CONSUMER: pure recurrence chain =================
        // lane = u*4 + gate  (gate: 0=i,1=f,2=g,3=o)
        const int gate_t = lane & 3;
        const int u      = lane >> 2;
        const int grow   = gate_t * 16 + u;
        const float nkl  = (gate_t == 2) ? NK_G : NK_IFO;    // matches producer prescale
        float whh[NH];
        #pragma unroll
        for (int j = 0; j < NH; j += 4) {
            float4 w4 = *(const float4*)(w_hh + grow * NH + j);
            whh[j]   = w4.x * nkl;
            whh[j+1] = w4.y * nkl;
            whh[j+2] = w4.z * nkl;
            whh[j+3] = w4.w * nkl;
        }
        // output constants: i,f,o -> sigma; g -> K*tanh  (K folded so C is pre-scaled)
        const bool  isg = (gate_t == 2);
        const float sO  = isg ? (2.f * KC) : 1.f;
        const float sB  = isg ? (-KC)      : 0.f;

        // swizzled chunk addresses for this lane's G row (row == lane)
        const int gkey = GKEY(lane);

        float C = 0.f;                 // pre-scaled cell state: C = K * c
        float hs[NH];
        #pragma unroll
        for (int j = 0; j < NH; ++j) hs[j] = 0.f;

        // Consumer waves are the critical path; keep priority over producers
        // (matters at barrier boundaries where roles mix). [T5]
        __builtin_amdgcn_s_setprio(1);

        __syncthreads();   // barrier 0: G[0] ready

        for (int g = 0; g < NGRP; ++g) {
            float gvv[16];
            #pragma unroll
            for (int q = 0; q < 4; ++q) {
                f32x4 g4 = *(f32x4*)&G[e][g & 1][lane * GSTRIDE + ((q ^ gkey) * 4)];
                gvv[q*4+0] = g4[0]; gvv[q*4+1] = g4[1]; gvv[q*4+2] = g4[2]; gvv[q*4+3] = g4[3];
            }

            float hstore[16];

            #pragma unroll
            for (int r = 0; r < 16; ++r) {
                // matvec: z' = gvv' + (whh*nk)·h, depth-5 (8 pairs + 3-level tree)
                float p0 = fmaf(hs[0],  whh[0],  gvv[r]);
                p0       = fmaf(hs[1],  whh[1],  p0);
                float p1 = hs[2]  * whh[2];   p1 = fmaf(hs[3],  whh[3],  p1);
                float p2 = hs[4]  * whh[4];   p2 = fmaf(hs[5],  whh[5],  p2);
                float p3 = hs[6]  * whh[6];   p3 = fmaf(hs[7],  whh[7],  p3);
                float p4 = hs[8]  * whh[8];   p4 = fmaf(hs[9],  whh[9],  p4);
                float p5 = hs[10] * whh[10];  p5 = fmaf(hs[11], whh[11], p5);
                float p6 = hs[12] * whh[12];  p6 = fmaf(hs[13], whh[13], p6);
                float p7 = hs[14] * whh[14];  p7 = fmaf(hs[15], whh[15], p7);
                const float s01 = p0 + p1, s23 = p2 + p3, s45 = p4 + p5, s67 = p6 + p7;
                const float zp  = (s01 + s23) + (s45 + s67);

                // act: i,f,o -> sigma(z); g -> K*tanh(z)   (exp2 arg pre-scaled)
                const float ex  = __builtin_amdgcn_exp2f(zp);
                const float act = fmaf(sO, __builtin_amdgcn_rcpf(1.f + ex), sB);

                // gather within 4-lane cluster (VALU DPP)
                const float ig = quad_bcast0(act);
                const float fg = quad_bcast1(act);
                const float gg = quad_bcast2(act);   // = K*tanh(g)
                const float og = quad_bcast3(act);

                // off-chain helpers during the exp2 latency
                const float igg = ig * gg;           // K * i * tanh(g)
                const float t2o = og + og;
                const float nog = -og;

                // pre-scaled cell update: C = f*C + K*i*tanh(g)  (C = K*c)
                C = fmaf(fg, C, igg);
                // h = o * tanh(c) = 2*o*rcp(1+e^{-2c}) - o ; exp2(C) = e^{-2c}
                const float e2 = __builtin_amdgcn_exp2f(C);
                const float r2 = __builtin_amdgcn_rcpf(1.f + e2);
                const float hn = fmaf(t2o, r2, nog);

                hstore[r] = hn;

                #pragma unroll
                for (int j = 0; j < NH; ++j) hs[j] = readlane_f(hn, 4 * j);
            }

            // batch h history to LDS. hn is identical across the 4-lane
            // cluster -> only gate_t==0 lanes store (kills the 4-way
            // same-address bank conflict; value unchanged).
            if (gate_t == 0) {
                #pragma unroll
                for (int r = 0; r < 16; ++r)
                    HT[e][g & 1][r * NH + u] = hstore[r];
            }

            __syncthreads();   // barrier g+1
        }
    }
}

extern "C" void kernel_launch(void* const* d_in, const int* in_sizes, int n_in,
                              void* d_out, int out_size, void* d_ws, size_t ws_size,
                              hipStream_t stream) {
    const float* x    = (const float*)d_in[0];
    const float* w_ih = (const float*)d_in[1];
    const float* w_hh = (const float*)d_in[2];
    const float* b_ih = (const float*)d_in[3];
    const float* b_hh = (const float*)d_in[4];
    const float* w_fc = (const float*)d_in[5];
    const float* b_fc = (const float*)d_in[6];
    float* out = (float*)d_out;

    hipLaunchKernelGGL(lstm_ws_kernel, dim3(NB / 4), dim3(512), 0, stream,
                       x, w_ih, w_hh, b_ih, b_hh, w_fc, b_fc, out);
}

// Round 5
// 246.493 us; speedup vs baseline: 1.0094x; 1.0094x over previous
//
#include <hip/hip_runtime.h>
#include <stdint.h>

#define SEQ   512
#define NB    1024
#define NIN   64
#define NH    16
#define NCLS  6
#define GSTRIDE 20   // floats per gate row in LDS (16 data + 4 pad)
#define NGRP  (SEQ / 16)

typedef __attribute__((ext_vector_type(8))) short short8;
typedef __attribute__((ext_vector_type(4))) float f32x4;

// constants: gate pre-acts are pre-scaled so exp2 consumes them directly.
// i,f,o: z' = -log2e * z      -> sigma(z)  = rcp(1+exp2(z'))
// g:     z' = -2*log2e * z    -> sigma(2z) = rcp(1+exp2(z')); tanh(z)=2r-1
// c kept pre-scaled by K = -2*log2e (so exp2(C) = e^{-2c}); g-lane output
// constants fold K: act_g = K*tanh(g) = 2K*r - K.
#define LOG2E   1.4426950408889634f
#define NK_IFO  (-1.4426950408889634f)
#define NK_G    (-2.8853900817779268f)
#define KC      (-2.8853900817779268f)

// G chunk swizzle: physical chunk = logical chunk ^ ((row>>3)&3).
// Rationale: row base banks (20*row mod 32) repeat with period 8, so rows
// {r, r+8, r+16, ...} share a bank base; XOR-rotating their chunk index
// spreads the 8 aliasing lanes across all 4 chunks -> 2-way max (free).
#define GKEY(row) (((row) >> 3) & 3)

__device__ __forceinline__ float readlane_f(float v, int l) {
    return __int_as_float(__builtin_amdgcn_readlane(__float_as_int(v), l));
}

// Split fp32 -> bf16 hi (RNE) + bf16 lo (residual); hi+lo reconstructs to
// ~2^-17 relative. v_cvt_pk_bf16_f32 packs 2 floats -> 2 bf16 per op:
// 24 VALU ops per 8 elements vs 40 for the shift/sub form.
__device__ __forceinline__ uint32_t cvt_pk_bf16(float a, float b) {
    uint32_t r;
    asm("v_cvt_pk_bf16_f32 %0, %1, %2" : "=v"(r) : "v"(a), "v"(b));
    return r;
}

__device__ __forceinline__ void split8(float4 u0, float4 u1, short8& hi, short8& lo) {
    float f[8] = {u0.x, u0.y, u0.z, u0.w, u1.x, u1.y, u1.z, u1.w};
    union { short8 s8; uint32_t u[4]; } H, L;
    #pragma unroll
    for (int k = 0; k < 4; ++k) {
        uint32_t pk = cvt_pk_bf16(f[2*k], f[2*k+1]);
        H.u[k] = pk;
        float hf0 = __uint_as_float(pk << 16);
        float hf1 = __uint_as_float(pk & 0xffff0000u);
        L.u[k] = cvt_pk_bf16(f[2*k] - hf0, f[2*k+1] - hf1);
    }
    hi = H.s8;
    lo = L.s8;
}

// quad_perm broadcast via update_dpp (R4/R5-verified on gfx950)
__device__ __forceinline__ float quad_bcast0(float v) {
    return __int_as_float(__builtin_amdgcn_update_dpp(0, __float_as_int(v), 0x00, 0xF, 0xF, true));
}
__device__ __forceinline__ float quad_bcast1(float v) {
    return __int_as_float(__builtin_amdgcn_update_dpp(0, __float_as_int(v), 0x55, 0xF, 0xF, true));
}
__device__ __forceinline__ float quad_bcast2(float v) {
    return __int_as_float(__builtin_amdgcn_update_dpp(0, __float_as_int(v), 0xAA, 0xF, 0xF, true));
}
__device__ __forceinline__ float quad_bcast3(float v) {
    return __int_as_float(__builtin_amdgcn_update_dpp(0, __float_as_int(v), 0xFF, 0xF, 0xF, true));
}

__global__ __launch_bounds__(512, 2)
void lstm_ws_kernel(const float* __restrict__ x,
                    const float* __restrict__ w_ih,
                    const float* __restrict__ w_hh,
                    const float* __restrict__ b_ih,
                    const float* __restrict__ b_hh,
                    const float* __restrict__ w_fc,
                    const float* __restrict__ b_fc,
                    float* __restrict__ out)
{
    __shared__ float G [4][2][64 * GSTRIDE];   // 40 KB, pre-scaled gates (chunk-swizzled)
    __shared__ float HT[4][2][16 * NH];        //  8 KB, h history

    const int tid  = threadIdx.x;
    const int wid  = tid >> 6;       // 0..7
    const int lane = tid & 63;
    // R3 mapping (verified best): producer wid 0-3 pairs with consumer wid 4-7
    // on the same SIMD (wid%4) -> 1 producer + 1 consumer per SIMD. R4's
    // role permutation (2 consumers/SIMD) regressed 50%: two chains on one
    // SIMD interleave at only ~1.35x the single-chain rate while leaving
    // producer SIMDs idle. Do not revisit.
    const int e    = wid & 3;        // batch element within block
    const int b    = blockIdx.x * 4 + e;
    const bool producer = (wid < 4);

    if (producer) {
        // ================= PRODUCER: x-GEMM + staging + FC =================
        const int ml   = lane & 15;      // MFMA A row (timestep) / B col
        const int half = lane >> 4;      // 0..3
        const int kk   = half * 8;

        short8 Bh[4][2], Bl[4][2];
        #pragma unroll
        for (int tau = 0; tau < 4; ++tau) {
            #pragma unroll
            for (int ch = 0; ch < 2; ++ch) {
                const float* wr = w_ih + (tau * 16 + ml) * NIN + ch * 32 + kk;
                float4 u0 = *(const float4*)wr;
                float4 u1 = *(const float4*)(wr + 4);
                split8(u0, u1, Bh[tau][ch], Bl[tau][ch]);
            }
        }
        // per-tile exp2 prescale + prescaled bias (gate row = tau*16 + ml; tau==2 is g)
        float nkt[4], bwk[4];
        int   gidx[4];   // swizzled chunk slot for this lane's 4 G rows
        #pragma unroll
        for (int tau = 0; tau < 4; ++tau) {
            nkt[tau] = (tau == 2) ? NK_G : NK_IFO;
            bwk[tau] = (b_ih[tau * 16 + ml] + b_hh[tau * 16 + ml]) * nkt[tau];
            const int row = ml * 4 + tau;
            gidx[tau] = row * GSTRIDE + (half ^ GKEY(row)) * 4;
        }

        const float* xbase = x + ((size_t)b * SEQ + ml) * NIN + kk;
        float4 px0 = *(const float4*)(xbase + 0);
        float4 px1 = *(const float4*)(xbase + 4);
        float4 px2 = *(const float4*)(xbase + 32);
        float4 px3 = *(const float4*)(xbase + 36);

        // prologue: compute G[0]
        {
            short8 a0h, a0l, a1h, a1l;
            split8(px0, px1, a0h, a0l);
            split8(px2, px3, a1h, a1l);
            #pragma unroll
            for (int tau = 0; tau < 4; ++tau) {
                f32x4 c_ = {0.f, 0.f, 0.f, 0.f};
                c_ = __builtin_amdgcn_mfma_f32_16x16x32_bf16(a0h, Bh[tau][0], c_, 0, 0, 0);
                c_ = __builtin_amdgcn_mfma_f32_16x16x32_bf16(a1h, Bh[tau][1], c_, 0, 0, 0);
                c_ = __builtin_amdgcn_mfma_f32_16x16x32_bf16(a0l, Bh[tau][0], c_, 0, 0, 0);
                c_ = __builtin_amdgcn_mfma_f32_16x16x32_bf16(a0h, Bl[tau][0], c_, 0, 0, 0);
                c_ = __builtin_amdgcn_mfma_f32_16x16x32_bf16(a1l, Bh[tau][1], c_, 0, 0, 0);
                c_ = __builtin_amdgcn_mfma_f32_16x16x32_bf16(a1h, Bl[tau][1], c_, 0, 0, 0);
                f32x4 s_;
                s_[0] = fmaf(c_[0], nkt[tau], bwk[tau]);
                s_[1] = fmaf(c_[1], nkt[tau], bwk[tau]);
                s_[2] = fmaf(c_[2], nkt[tau], bwk[tau]);
                s_[3] = fmaf(c_[3], nkt[tau], bwk[tau]);
                *(f32x4*)&G[e][0][gidx[tau]] = s_;
            }
        }
        {
            const float* xp = xbase + (size_t)16 * NIN;
            px0 = *(const float4*)(xp + 0);
            px1 = *(const float4*)(xp + 4);
            px2 = *(const float4*)(xp + 32);
            px3 = *(const float4*)(xp + 36);
        }
        __syncthreads();   // barrier 0: G[0] ready

        float accfc[NCLS];
        #pragma unroll
        for (int cls = 0; cls < NCLS; ++cls) accfc[cls] = 0.f;

        for (int g = 0; g < NGRP; ++g) {
            if (g < NGRP - 1) {
                short8 a0h, a0l, a1h, a1l;
                split8(px0, px1, a0h, a0l);
                split8(px2, px3, a1h, a1l);
                if (g < NGRP - 2) {
                    const float* xp = xbase + (size_t)(g + 2) * 16 * NIN;
                    px0 = *(const float4*)(xp + 0);
                    px1 = *(const float4*)(xp + 4);
                    px2 = *(const float4*)(xp + 32);
                    px3 = *(const float4*)(xp + 36);
                }
                #pragma unroll
                for (int tau = 0; tau < 4; ++tau) {
                    f32x4 c_ = {0.f, 0.f, 0.f, 0.f};
                    c_ = __builtin_amdgcn_mfma_f32_16x16x32_bf16(a0h, Bh[tau][0], c_, 0, 0, 0);
                    c_ = __builtin_amdgcn_mfma_f32_16x16x32_bf16(a1h, Bh[tau][1], c_, 0, 0, 0);
                    c_ = __builtin_amdgcn_mfma_f32_16x16x32_bf16(a0l, Bh[tau][0], c_, 0, 0, 0);
                    c_ = __builtin_amdgcn_mfma_f32_16x16x32_bf16(a0h, Bl[tau][0], c_, 0, 0, 0);
                    c_ = __builtin_amdgcn_mfma_f32_16x16x32_bf16(a1l, Bh[tau][1], c_, 0, 0, 0);
                    c_ = __builtin_amdgcn_mfma_f32_16x16x32_bf16(a1h, Bl[tau][1], c_, 0, 0, 0);
                    f32x4 s_;
                    s_[0] = fmaf(c_[0], nkt[tau], bwk[tau]);
                    s_[1] = fmaf(c_[1], nkt[tau], bwk[tau]);
                    s_[2] = fmaf(c_[2], nkt[tau], bwk[tau]);
                    s_[3] = fmaf(c_[3], nkt[tau], bwk[tau]);
                    *(f32x4*)&G[e][(g + 1) & 1][gidx[tau]] = s_;
                }
            }
            if (g > 0) {
                const int gp = g - 1;
                float4 h4 = *(float4*)&HT[e][gp & 1][lane * 4];
                #pragma unroll
                for (int cls = 0; cls < NCLS; ++cls) {
                    float4 wf = *(const float4*)(w_fc + cls * (SEQ * NH) + gp * 256 + lane * 4);
                    accfc[cls] = fmaf(h4.x, wf.x, accfc[cls]);
                    accfc[cls] = fmaf(h4.y, wf.y, accfc[cls]);
                    accfc[cls] = fmaf(h4.z, wf.z, accfc[cls]);
                    accfc[cls] = fmaf(h4.w, wf.w, accfc[cls]);
                }
            }
            __syncthreads();   // barrier g+1
        }
        {
            const int gp = NGRP - 1;
            float4 h4 = *(float4*)&HT[e][gp & 1][lane * 4];
            #pragma unroll
            for (int cls = 0; cls < NCLS; ++cls) {
                float4 wf = *(const float4*)(w_fc + cls * (SEQ * NH) + gp * 256 + lane * 4);
                accfc[cls] = fmaf(h4.x, wf.x, accfc[cls]);
                accfc[cls] = fmaf(h4.y, wf.y, accfc[cls]);
                accfc[cls] = fmaf(h4.z, wf.z, accfc[cls]);
                accfc[cls] = fmaf(h4.w, wf.w, accfc[cls]);
            }
        }
        #pragma unroll
        for (int cls = 0; cls < NCLS; ++cls) {
            float v = accfc[cls];
            v += __shfl_xor(v, 1);
            v += __shfl_xor(v, 2);
            v += __shfl_xor(v, 4);
            v += __shfl_xor(v, 8);
            v += __shfl_xor(v, 16);
            v += __shfl_xor(v, 32);
            accfc[cls] = v;
        }
        if (lane == 0) {
            #pragma unroll
            for (int cls = 0; cls < NCLS; ++cls)
                out[b * NCLS + cls] = accfc[cls] + b_fc[cls];
        }
    } else {
        // ================= CONSUMER: pure recurrence chain =================
        // lane = u*4 + gate  (gate: 0=i,1=f,2=g,3=o)
        const int gate_t = lane & 3;
        const int u      = lane >> 2;
        const int grow   = gate_t * 16 + u;
        const float nkl  = (gate_t == 2) ? NK_G : NK_IFO;    // matches producer prescale
        float whh[NH];
        #pragma unroll
        for (int j = 0; j < NH; j += 4) {
            float4 w4 = *(const float4*)(w_hh + grow * NH + j);
            whh[j]   = w4.x * nkl;
            whh[j+1] = w4.y * nkl;
            whh[j+2] = w4.z * nkl;
            whh[j+3] = w4.w * nkl;
        }
        // output constants: i,f,o -> sigma; g -> K*tanh  (K folded so C is pre-scaled)
        const bool  isg = (gate_t == 2);
        const float sO  = isg ? (2.f * KC) : 1.f;
        const float sB  = isg ? (-KC)      : 0.f;

        // swizzled chunk addresses for this lane's G row (row == lane)
        const int gkey = GKEY(lane);

        float C = 0.f;                 // pre-scaled cell state: C = K * c
        float hs[NH];
        #pragma unroll
        for (int j = 0; j < NH; ++j) hs[j] = 0.f;

        // Consumer wave is the critical path 100% of the time; its SIMD-mate
        // is the paired producer. Prioritize the chain so producer bursts
        // can't delay dependent chain ops. [T5, +4% verified R3]
        __builtin_amdgcn_s_setprio(1);

        __syncthreads();   // barrier 0: G[0] ready

        for (int g = 0; g < NGRP; ++g) {
            float gvv[16];
            #pragma unroll
            for (int q = 0; q < 4; ++q) {
                f32x4 g4 = *(f32x4*)&G[e][g & 1][lane * GSTRIDE + ((q ^ gkey) * 4)];
                gvv[q*4+0] = g4[0]; gvv[q*4+1] = g4[1]; gvv[q*4+2] = g4[2]; gvv[q*4+3] = g4[3];
            }

            float hstore[16];

            #pragma unroll
            for (int r = 0; r < 16; ++r) {
                // matvec: z' = gvv' + (whh*nk)·h, depth-5 (8 pairs + 3-level tree)
                float p0 = fmaf(hs[0],  whh[0],  gvv[r]);
                p0       = fmaf(hs[1],  whh[1],  p0);
                float p1 = hs[2]  * whh[2];   p1 = fmaf(hs[3],  whh[3],  p1);
                float p2 = hs[4]  * whh[4];   p2 = fmaf(hs[5],  whh[5],  p2);
                float p3 = hs[6]  * whh[6];   p3 = fmaf(hs[7],  whh[7],  p3);
                float p4 = hs[8]  * whh[8];   p4 = fmaf(hs[9],  whh[9],  p4);
                float p5 = hs[10] * whh[10];  p5 = fmaf(hs[11], whh[11], p5);
                float p6 = hs[12] * whh[12];  p6 = fmaf(hs[13], whh[13], p6);
                float p7 = hs[14] * whh[14];  p7 = fmaf(hs[15], whh[15], p7);
                const float s01 = p0 + p1, s23 = p2 + p3, s45 = p4 + p5, s67 = p6 + p7;
                const float zp  = (s01 + s23) + (s45 + s67);

                // act: i,f,o -> sigma(z); g -> K*tanh(z)   (exp2 arg pre-scaled)
                const float ex  = __builtin_amdgcn_exp2f(zp);
                const float act = fmaf(sO, __builtin_amdgcn_rcpf(1.f + ex), sB);

                // gather within 4-lane cluster (VALU DPP)
                const float ig = quad_bcast0(act);
                const float fg = quad_bcast1(act);
                const float gg = quad_bcast2(act);   // = K*tanh(g)
                const float og = quad_bcast3(act);

                // off-chain helpers during the exp2 latency
                const float igg = ig * gg;           // K * i * tanh(g)
                const float t2o = og + og;
                const float nog = -og;

                // pre-scaled cell update: C = f*C + K*i*tanh(g)  (C = K*c)
                C = fmaf(fg, C, igg);
                // h = o * tanh(c) = 2*o*rcp(1+e^{-2c}) - o ; exp2(C) = e^{-2c}
                const float e2 = __builtin_amdgcn_exp2f(C);
                const float r2 = __builtin_amdgcn_rcpf(1.f + e2);
                const float hn = fmaf(t2o, r2, nog);

                hstore[r] = hn;

                #pragma unroll
                for (int j = 0; j < NH; ++j) hs[j] = readlane_f(hn, 4 * j);
            }

            // batch h history to LDS. hn is identical across the 4-lane
            // cluster -> only gate_t==0 lanes store.
            if (gate_t == 0) {
                #pragma unroll
                for (int r = 0; r < 16; ++r)
                    HT[e][g & 1][r * NH + u] = hstore[r];
            }

            __syncthreads();   // barrier g+1
        }
    }
}

extern "C" void kernel_launch(void* const* d_in, const int* in_sizes, int n_in,
                              void* d_out, int out_size, void* d_ws, size_t ws_size,
                              hipStream_t stream) {
    const float* x    = (const float*)d_in[0];
    const float* w_ih = (const float*)d_in[1];
    const float* w_hh = (const float*)d_in[2];
    const float* b_ih = (const float*)d_in[3];
    const float* b_hh = (const float*)d_in[4];
    const float* w_fc = (const float*)d_in[5];
    const float* b_fc = (const float*)d_in[6];
    float* out = (float*)d_out;

    hipLaunchKernelGGL(lstm_ws_kernel, dim3(NB / 4), dim3(512), 0, stream,
                       x, w_ih, w_hh, b_ih, b_hh, w_fc, b_fc, out);
}

// Round 6
// 220.267 us; speedup vs baseline: 1.1296x; 1.1191x over previous
//
#include <hip/hip_runtime.h>
#include <stdint.h>

#define SEQ   512
#define NB    1024
#define NIN   64
#define NH    16
#define NCLS  6
#define GSTRIDE 20   // floats per gate row in LDS (16 data + 4 pad)
#define GBLK  32     // timesteps per group (32-step groups halve barrier count)
#define NGRP  (SEQ / GBLK)

typedef __attribute__((ext_vector_type(8))) short short8;
typedef __attribute__((ext_vector_type(4))) float f32x4;

// constants: gate pre-acts are pre-scaled so exp2 consumes them directly.
// i,f,o: z' = -log2e * z      -> sigma(z)  = rcp(1+exp2(z'))
// g:     z' = -2*log2e * z    -> sigma(2z) = rcp(1+exp2(z')); tanh(z)=2r-1
// c kept pre-scaled by K = -2*log2e (so exp2(C) = e^{-2c}); g-lane output
// constants fold K: act_g = K*tanh(g) = 2K*r - K.
#define LOG2E   1.4426950408889634f
#define NK_IFO  (-1.4426950408889634f)
#define NK_G    (-2.8853900817779268f)
#define KC      (-2.8853900817779268f)

// G chunk swizzle: physical chunk = logical chunk ^ ((row>>3)&3).
// Bank base (20*row mod 32) repeats with period 8; XOR-rotating the chunk
// spreads the 8 aliasing lanes across all 4 chunks -> 2-way max (free).
// Invariant: GKEY(row+64) == GKEY(row), so 128-row buffers need no change.
#define GKEY(row) (((row) >> 3) & 3)

__device__ __forceinline__ float readlane_f(float v, int l) {
    return __int_as_float(__builtin_amdgcn_readlane(__float_as_int(v), l));
}

// Split fp32 -> bf16 hi + bf16 lo (truncation split; residual ~2^-16 relative).
// NOTE (R5): an inline-asm v_cvt_pk_bf16_f32 version (fewer ops) regressed
// 82->103 us — asm blocks perturb hipcc's scheduling/regalloc of the whole
// kernel. Keep the plain bit-twiddle form. [rule: m240 / T12]
__device__ __forceinline__ void split8(float4 u0, float4 u1, short8& hi, short8& lo) {
    float f[8] = {u0.x, u0.y, u0.z, u0.w, u1.x, u1.y, u1.z, u1.w};
    #pragma unroll
    for (int j = 0; j < 8; ++j) {
        uint32_t b = __float_as_uint(f[j]);
        uint16_t hb = (uint16_t)(b >> 16);
        hi[j] = (short)hb;
        float hf = __uint_as_float(((uint32_t)hb) << 16);
        lo[j] = (short)(uint16_t)(__float_as_uint(f[j] - hf) >> 16);
    }
}

// quad_perm broadcast via update_dpp (R4/R5-verified on gfx950)
__device__ __forceinline__ float quad_bcast0(float v) {
    return __int_as_float(__builtin_amdgcn_update_dpp(0, __float_as_int(v), 0x00, 0xF, 0xF, true));
}
__device__ __forceinline__ float quad_bcast1(float v) {
    return __int_as_float(__builtin_amdgcn_update_dpp(0, __float_as_int(v), 0x55, 0xF, 0xF, true));
}
__device__ __forceinline__ float quad_bcast2(float v) {
    return __int_as_float(__builtin_amdgcn_update_dpp(0, __float_as_int(v), 0xAA, 0xF, 0xF, true));
}
__device__ __forceinline__ float quad_bcast3(float v) {
    return __int_as_float(__builtin_amdgcn_update_dpp(0, __float_as_int(v), 0xFF, 0xF, 0xF, true));
}

// producer helpers: load one 16-step x tile, compute one 16-step gate tile
#define LOAD_TILE(P0, P1, P2, P3, T) do {                       \
    const float* xp_ = xbase + (size_t)(T) * 16 * NIN;          \
    P0 = *(const float4*)(xp_ + 0);                             \
    P1 = *(const float4*)(xp_ + 4);                             \
    P2 = *(const float4*)(xp_ + 32);                            \
    P3 = *(const float4*)(xp_ + 36);                            \
} while (0)

#define COMPUTE_TILE(P0, P1, P2, P3, GB, ROWOFF) do {                          \
    short8 a0h_, a0l_, a1h_, a1l_;                                             \
    split8(P0, P1, a0h_, a0l_);                                                \
    split8(P2, P3, a1h_, a1l_);                                                \
    _Pragma("unroll")                                                          \
    for (int tau = 0; tau < 4; ++tau) {                                        \
        f32x4 c_ = {0.f, 0.f, 0.f, 0.f};                                       \
        c_ = __builtin_amdgcn_mfma_f32_16x16x32_bf16(a0h_, Bh[tau][0], c_, 0, 0, 0); \
        c_ = __builtin_amdgcn_mfma_f32_16x16x32_bf16(a1h_, Bh[tau][1], c_, 0, 0, 0); \
        c_ = __builtin_amdgcn_mfma_f32_16x16x32_bf16(a0l_, Bh[tau][0], c_, 0, 0, 0); \
        c_ = __builtin_amdgcn_mfma_f32_16x16x32_bf16(a0h_, Bl[tau][0], c_, 0, 0, 0); \
        c_ = __builtin_amdgcn_mfma_f32_16x16x32_bf16(a1l_, Bh[tau][1], c_, 0, 0, 0); \
        c_ = __builtin_amdgcn_mfma_f32_16x16x32_bf16(a1h_, Bl[tau][1], c_, 0, 0, 0); \
        f32x4 s_;                                                              \
        s_[0] = fmaf(c_[0], nkt[tau], bwk[tau]);                               \
        s_[1] = fmaf(c_[1], nkt[tau], bwk[tau]);                               \
        s_[2] = fmaf(c_[2], nkt[tau], bwk[tau]);                               \
        s_[3] = fmaf(c_[3], nkt[tau], bwk[tau]);                               \
        *(f32x4*)&(GB)[(ROWOFF) + gidx[tau]] = s_;                             \
    }                                                                          \
} while (0)

__global__ __launch_bounds__(512, 2)
void lstm_ws_kernel(const float* __restrict__ x,
                    const float* __restrict__ w_ih,
                    const float* __restrict__ w_hh,
                    const float* __restrict__ b_ih,
                    const float* __restrict__ b_hh,
                    const float* __restrict__ w_fc,
                    const float* __restrict__ b_fc,
                    float* __restrict__ out)
{
    __shared__ float G [4][2][128 * GSTRIDE];   // 80 KB, pre-scaled gates (chunk-swizzled)
    __shared__ float HT[4][2][GBLK * NH];       // 16 KB, h history

    const int tid  = threadIdx.x;
    const int wid  = tid >> 6;       // 0..7
    const int lane = tid & 63;
    // R3 mapping (verified best): producer wid 0-3 pairs with consumer wid 4-7
    // on the same SIMD (wid%4) -> 1 producer + 1 consumer per SIMD. R4's
    // 2-consumers/SIMD permutation regressed 50%. Do not revisit.
    const int e    = wid & 3;        // batch element within block
    const int b    = blockIdx.x * 4 + e;
    const bool producer = (wid < 4);

    if (producer) {
        // ================= PRODUCER: x-GEMM + staging + FC =================
        const int ml   = lane & 15;      // MFMA A row (timestep) / B col
        const int half = lane >> 4;      // 0..3
        const int kk   = half * 8;

        short8 Bh[4][2], Bl[4][2];
        #pragma unroll
        for (int tau = 0; tau < 4; ++tau) {
            #pragma unroll
            for (int ch = 0; ch < 2; ++ch) {
                const float* wr = w_ih + (tau * 16 + ml) * NIN + ch * 32 + kk;
                float4 u0 = *(const float4*)wr;
                float4 u1 = *(const float4*)(wr + 4);
                split8(u0, u1, Bh[tau][ch], Bl[tau][ch]);
            }
        }
        // per-tile exp2 prescale + prescaled bias (gate row = tau*16 + ml; tau==2 is g)
        float nkt[4], bwk[4];
        int   gidx[4];   // swizzled slot for this lane's 4 G rows (subtile 0)
        #pragma unroll
        for (int tau = 0; tau < 4; ++tau) {
            nkt[tau] = (tau == 2) ? NK_G : NK_IFO;
            bwk[tau] = (b_ih[tau * 16 + ml] + b_hh[tau * 16 + ml]) * nkt[tau];
            const int row = ml * 4 + tau;
            gidx[tau] = row * GSTRIDE + (half ^ GKEY(row)) * 4;
        }

        const float* xbase = x + ((size_t)b * SEQ + ml) * NIN + kk;

        float4 a0, a1, a2, a3;   // tile buffer A
        float4 b0, b1, b2, b3;   // tile buffer B

        // prologue: group 0 = tiles 0,1 -> G[e][0]; prefetch tile 2
        LOAD_TILE(a0, a1, a2, a3, 0);
        LOAD_TILE(b0, b1, b2, b3, 1);
        COMPUTE_TILE(a0, a1, a2, a3, G[e][0], 0);
        LOAD_TILE(a0, a1, a2, a3, 2);
        COMPUTE_TILE(b0, b1, b2, b3, G[e][0], 64 * GSTRIDE);
        __syncthreads();   // barrier 0: G[0] ready

        float accfc[NCLS];
        #pragma unroll
        for (int cls = 0; cls < NCLS; ++cls) accfc[cls] = 0.f;

        for (int g = 0; g < NGRP; ++g) {
            if (g < NGRP - 1) {
                // group g+1 = tiles 2g+2 (in A regs), 2g+3
                LOAD_TILE(b0, b1, b2, b3, 2 * g + 3);
                COMPUTE_TILE(a0, a1, a2, a3, G[e][(g + 1) & 1], 0);
                if (g < NGRP - 2)
                    LOAD_TILE(a0, a1, a2, a3, 2 * g + 4);
                COMPUTE_TILE(b0, b1, b2, b3, G[e][(g + 1) & 1], 64 * GSTRIDE);
            }
            if (g > 0) {
                const int gp = g - 1;
                float4 h4a = *(float4*)&HT[e][gp & 1][lane * 4];
                float4 h4b = *(float4*)&HT[e][gp & 1][256 + lane * 4];
                #pragma unroll
                for (int cls = 0; cls < NCLS; ++cls) {
                    const float* wf = w_fc + cls * (SEQ * NH) + gp * (GBLK * NH);
                    float4 wfa = *(const float4*)(wf + lane * 4);
                    float4 wfb = *(const float4*)(wf + 256 + lane * 4);
                    accfc[cls] = fmaf(h4a.x, wfa.x, accfc[cls]);
                    accfc[cls] = fmaf(h4a.y, wfa.y, accfc[cls]);
                    accfc[cls] = fmaf(h4a.z, wfa.z, accfc[cls]);
                    accfc[cls] = fmaf(h4a.w, wfa.w, accfc[cls]);
                    accfc[cls] = fmaf(h4b.x, wfb.x, accfc[cls]);
                    accfc[cls] = fmaf(h4b.y, wfb.y, accfc[cls]);
                    accfc[cls] = fmaf(h4b.z, wfb.z, accfc[cls]);
                    accfc[cls] = fmaf(h4b.w, wfb.w, accfc[cls]);
                }
            }
            __syncthreads();   // barrier g+1
        }
        {
            const int gp = NGRP - 1;
            float4 h4a = *(float4*)&HT[e][gp & 1][lane * 4];
            float4 h4b = *(float4*)&HT[e][gp & 1][256 + lane * 4];
            #pragma unroll
            for (int cls = 0; cls < NCLS; ++cls) {
                const float* wf = w_fc + cls * (SEQ * NH) + gp * (GBLK * NH);
                float4 wfa = *(const float4*)(wf + lane * 4);
                float4 wfb = *(const float4*)(wf + 256 + lane * 4);
                accfc[cls] = fmaf(h4a.x, wfa.x, accfc[cls]);
                accfc[cls] = fmaf(h4a.y, wfa.y, accfc[cls]);
                accfc[cls] = fmaf(h4a.z, wfa.z, accfc[cls]);
                accfc[cls] = fmaf(h4a.w, wfa.w, accfc[cls]);
                accfc[cls] = fmaf(h4b.x, wfb.x, accfc[cls]);
                accfc[cls] = fmaf(h4b.y, wfb.y, accfc[cls]);
                accfc[cls] = fmaf(h4b.z, wfb.z, accfc[cls]);
                accfc[cls] = fmaf(h4b.w, wfb.w, accfc[cls]);
            }
        }
        #pragma unroll
        for (int cls = 0; cls < NCLS; ++cls) {
            float v = accfc[cls];
            v += __shfl_xor(v, 1);
            v += __shfl_xor(v, 2);
            v += __shfl_xor(v, 4);
            v += __shfl_xor(v, 8);
            v += __shfl_xor(v, 16);
            v += __shfl_xor(v, 32);
            accfc[cls] = v;
        }
        if (lane == 0) {
            #pragma unroll
            for (int cls = 0; cls < NCLS; ++cls)
                out[b * NCLS + cls] = accfc[cls] + b_fc[cls];
        }
    } else {
        // ================= CONSUMER: pure recurrence chain =================
        // lane = u*4 + gate  (gate: 0=i,1=f,2=g,3=o)
        const int gate_t = lane & 3;
        const int u      = lane >> 2;
        const int grow   = gate_t * 16 + u;
        const float nkl  = (gate_t == 2) ? NK_G : NK_IFO;    // matches producer prescale
        float whh[NH];
        #pragma unroll
        for (int j = 0; j < NH; j += 4) {
            float4 w4 = *(const float4*)(w_hh + grow * NH + j);
            whh[j]   = w4.x * nkl;
            whh[j+1] = w4.y * nkl;
            whh[j+2] = w4.z * nkl;
            whh[j+3] = w4.w * nkl;
        }
        // output constants: i,f,o -> sigma; g -> K*tanh  (K folded so C is pre-scaled)
        const bool  isg = (gate_t == 2);
        const float sO  = isg ? (2.f * KC) : 1.f;
        const float sB  = isg ? (-KC)      : 0.f;

        // swizzled chunk key for this lane's G rows (row = lane and lane+64;
        // GKEY identical for both)
        const int gkey = GKEY(lane);

        float C = 0.f;                 // pre-scaled cell state: C = K * c
        float hs[NH];
        #pragma unroll
        for (int j = 0; j < NH; ++j) hs[j] = 0.f;

        // Consumer wave is the critical path 100% of the time; its SIMD-mate
        // is the paired producer. Prioritize the chain. [T5, +4% verified R3]
        __builtin_amdgcn_s_setprio(1);

        __syncthreads();   // barrier 0: G[0] ready

        for (int g = 0; g < NGRP; ++g) {
            float gvv[GBLK];
            #pragma unroll
            for (int q = 0; q < 8; ++q) {
                f32x4 g4 = *(f32x4*)&G[e][g & 1][(q >> 2) * 64 * GSTRIDE +
                                                 lane * GSTRIDE + (((q & 3) ^ gkey) * 4)];
                gvv[q*4+0] = g4[0]; gvv[q*4+1] = g4[1]; gvv[q*4+2] = g4[2]; gvv[q*4+3] = g4[3];
            }

            float hstore[GBLK];

            #pragma unroll
            for (int r = 0; r < GBLK; ++r) {
                // matvec: z' = gvv' + (whh*nk)·h, depth-5 (8 pairs + 3-level tree)
                float p0 = fmaf(hs[0],  whh[0],  gvv[r]);
                p0       = fmaf(hs[1],  whh[1],  p0);
                float p1 = hs[2]  * whh[2];   p1 = fmaf(hs[3],  whh[3],  p1);
                float p2 = hs[4]  * whh[4];   p2 = fmaf(hs[5],  whh[5],  p2);
                float p3 = hs[6]  * whh[6];   p3 = fmaf(hs[7],  whh[7],  p3);
                float p4 = hs[8]  * whh[8];   p4 = fmaf(hs[9],  whh[9],  p4);
                float p5 = hs[10] * whh[10];  p5 = fmaf(hs[11], whh[11], p5);
                float p6 = hs[12] * whh[12];  p6 = fmaf(hs[13], whh[13], p6);
                float p7 = hs[14] * whh[14];  p7 = fmaf(hs[15], whh[15], p7);
                const float s01 = p0 + p1, s23 = p2 + p3, s45 = p4 + p5, s67 = p6 + p7;
                const float zp  = (s01 + s23) + (s45 + s67);

                // act: i,f,o -> sigma(z); g -> K*tanh(z)   (exp2 arg pre-scaled)
                const float ex  = __builtin_amdgcn_exp2f(zp);
                const float act = fmaf(sO, __builtin_amdgcn_rcpf(1.f + ex), sB);

                // gather within 4-lane cluster (VALU DPP)
                const float ig = quad_bcast0(act);
                const float fg = quad_bcast1(act);
                const float gg = quad_bcast2(act);   // = K*tanh(g)
                const float og = quad_bcast3(act);

                // off-chain helpers during the exp2 latency
                const float igg = ig * gg;           // K * i * tanh(g)
                const float t2o = og + og;
                const float nog = -og;

                // pre-scaled cell update: C = f*C + K*i*tanh(g)  (C = K*c)
                C = fmaf(fg, C, igg);
                // h = o * tanh(c) = 2*o*rcp(1+e^{-2c}) - o ; exp2(C) = e^{-2c}
                const float e2 = __builtin_amdgcn_exp2f(C);
                const float r2 = __builtin_amdgcn_rcpf(1.f + e2);
                const float hn = fmaf(t2o, r2, nog);

                hstore[r] = hn;

                #pragma unroll
                for (int j = 0; j < NH; ++j) hs[j] = readlane_f(hn, 4 * j);
            }

            // batch h history to LDS. hn identical across the 4-lane cluster
            // -> only gate_t==0 lanes store.
            if (gate_t == 0) {
                #pragma unroll
                for (int r = 0; r < GBLK; ++r)
                    HT[e][g & 1][r * NH + u] = hstore[r];
            }

            __syncthreads();   // barrier g+1
        }
    }
}

extern "C" void kernel_launch(void* const* d_in, const int* in_sizes, int n_in,
                              void* d_out, int out_size, void* d_ws, size_t ws_size,
                              hipStream_t stream) {
    const float* x    = (const float*)d_in[0];
    const float* w_ih = (const float*)d_in[1];
    const float* w_hh = (const float*)d_in[2];
    const float* b_ih = (const float*)d_in[3];
    const float* b_hh = (const float*)d_in[4];
    const float* w_fc = (const float*)d_in[5];
    const float* b_fc = (const float*)d_in[6];
    float* out = (float*)d_out;

    hipLaunchKernelGGL(lstm_ws_kernel, dim3(NB / 4), dim3(512), 0, stream,
                       x, w_ih, w_hh, b_ih, b_hh, w_fc, b_fc, out);
}